// Round 2
// 823.097 us; speedup vs baseline: 5.5964x; 5.5964x over previous
//
#include <hip/hip_runtime.h>

typedef unsigned short u16;
typedef unsigned int   u32;

// B_=512, N=392, C=128, nH=4, hd=32, nW=128
#define NTOK   392
#define NN2    153664      // 392*392
#define QSCALE 0.17677669529663687f
#define LOG2E  1.44269504088896340736f

typedef __attribute__((ext_vector_type(8))) __bf16 bf16x8;
typedef __attribute__((ext_vector_type(4))) float  f32x4;
#define MFMA16(a,b,c) __builtin_amdgcn_mfma_f32_16x16x32_bf16((a),(b),(c),0,0,0)

__device__ __forceinline__ float bf2f(u16 u){
    union { u32 i; float f; } v; v.i = ((u32)u) << 16; return v.f;
}
__device__ __forceinline__ u16 f2bf(float x){
    union { float f; u32 i; } v; v.f = x;
    u32 r = (v.i + 0x7FFFu + ((v.i >> 16) & 1u)) >> 16;
    return (u16)r;
}
// adaptive loads/stores: isb=1 -> packed bf16 storage, isb=0 -> fp32 storage
__device__ __forceinline__ float ldf(const void* p, int isb, long i){
    if (isb) return bf2f(((const u16*)p)[i]);
    else     return ((const float*)p)[i];
}
__device__ __forceinline__ void stf(void* p, int isb, long i, float v){
    if (isb) ((u16*)p)[i] = f2bf(v);
    else     ((float*)p)[i] = v;
}

// load 8 consecutive values from global, split into hi/lo bf16 fragments.
// (bf16 storage -> lo = 0 exactly; fp32 -> hi+lo reproduces fp32 to ~2^-18)
__device__ __forceinline__ void ld8s(const void* p, int isb, long i0,
                                     bf16x8* h, bf16x8* l){
    union { u16 u[8]; bf16x8 v; } H, L;
    if (isb){
        const uint2* q = (const uint2*)((const u16*)p + i0);
        uint2 a = q[0], b = q[1];
        H.u[0]=(u16)a.x; H.u[1]=(u16)(a.x>>16); H.u[2]=(u16)a.y; H.u[3]=(u16)(a.y>>16);
        H.u[4]=(u16)b.x; H.u[5]=(u16)(b.x>>16); H.u[6]=(u16)b.y; H.u[7]=(u16)(b.y>>16);
        #pragma unroll
        for (int j = 0; j < 8; ++j) L.u[j] = 0;
    } else {
        const float4* q = (const float4*)((const float*)p + i0);
        float4 a = q[0], b = q[1];
        float f[8] = {a.x,a.y,a.z,a.w,b.x,b.y,b.z,b.w};
        #pragma unroll
        for (int j = 0; j < 8; ++j){
            u16 hh = f2bf(f[j]);
            H.u[j] = hh;
            L.u[j] = f2bf(f[j] - bf2f(hh));
        }
    }
    *h = H.v; *l = L.v;
}

// ---------- kernel A: storage-dtype detection on x ----------
__device__ __forceinline__ int plaus(u16 w){
    int e = (w >> 7) & 0xFF;
    return (w == 0) || (e >= 96 && e <= 145);
}
__global__ __launch_bounds__(256) void prep_kernel(
        const u16* __restrict__ x, int* __restrict__ flags){
    __shared__ int cnt[2];
    int tid = threadIdx.x;
    if (tid < 2) cnt[tid] = 0;
    __syncthreads();
    int p = plaus(x[tid]) + plaus(x[tid + 256]);
    if (p) atomicAdd(&cnt[0], p);
    int ez = ((tid & 1) == 0 && x[tid] == 0) + (((tid + 256) & 1) == 0 && x[tid + 256] == 0);
    if (ez) atomicAdd(&cnt[1], ez);
    __syncthreads();
    if (tid == 0){
        flags[0] = (cnt[1] < 64 && cnt[0] >= 436) ? 1 : 0;
        flags[4] = 0;
    }
}

// ---------- kernel B: mask nonzero scan ----------
__global__ __launch_bounds__(256) void mask_scan_kernel(
        const u32* __restrict__ m, int nhalf, const int* __restrict__ flagsRO,
        int* __restrict__ flags){
    long nw = flagsRO[0] ? nhalf : 2L * nhalf;
    long i0 = (long)blockIdx.x * 256 + threadIdx.x;
    u32 acc = 0;
    for (long i = i0; i < nw; i += (long)gridDim.x * 256) acc |= m[i];
    if (acc) atomicOr(&flags[4], 1);
}

// ---------- kernel C: expand relative-position bias (fp32) ----------
__global__ __launch_bounds__(256) void bias_expand_kernel(
        const int* __restrict__ rel_index, const void* btabP,
        const int* __restrict__ flags, float* __restrict__ biasfull){
    int idx = blockIdx.x * 256 + threadIdx.x;
    int isb = flags[0];
    if (idx < NN2){
        int t = rel_index[idx];
        #pragma unroll
        for (int h = 0; h < 4; ++h)
            biasfull[(long)h * NN2 + idx] = ldf(btabP, isb, (long)t * 4 + h);
    }
}

// ---------- kernel D: fused MFMA window attention ----------
// block = (head h, window b_), 512 threads = 8 waves, 1 block/CU.
// Phase 1: Q,K,V = x @ W^T via split hi/lo bf16 MFMA (fp32-equivalent precision).
//   Q/K stored [tok][32] bf16 (stride 40), V stored transposed [32][tok] (stride 424,
//   pad cols 392..423 zeroed). Keys padded to 416 = 26 x 16 (Kh rows 392..415 garbage,
//   gated by p=0 since key >= NTOK).
// Phase 2: each wave owns 16 q-rows. Per PAIR of 16-key QK^T tiles (MFMA K=32!):
//   two QK^T MFMAs -> +bias -> exp -> 16x32 P tile bounced through per-wave LDS
//   (D-layout -> A-layout transpose) -> one PV MFMA pair over all 32 k-lanes.
__global__ __launch_bounds__(512) void attn_mfma_kernel(
        const void* xP, const void* qwP, const void* maskP,
        const float* __restrict__ biasfull, const int* __restrict__ flags,
        void* outP){
    __shared__ __align__(16) u16 Qh[400 * 40];        // 32000 B  Q bf16 [tok][d]
    __shared__ __align__(16) u16 Kh[416 * 40];        // 33280 B  K bf16 [key][d]
    __shared__ __align__(16) u16 VT[32 * 424];        // 27136 B  V bf16 [d][key]
    __shared__ __align__(16) u16 uni[2 * 64 * 136];   // 34816 B  xs_hi/xs_lo; ph2: P bounce
    // total 127232 B -> 1 block/CU, 8 waves

    u16* xs_hi = uni;
    u16* xs_lo = uni + 64 * 136;

    const int tid  = threadIdx.x;
    const int lane = tid & 63;
    const int wv   = tid >> 6;          // 0..7
    const int c    = lane & 15;         // MFMA col / A-row lane id
    const int g    = lane >> 4;         // MFMA k-group (k = 8g..8g+7)
    const int h    = blockIdx.x;
    const int b_   = blockIdx.y;
    const int wdx  = b_ & 127;
    const int isb  = flags[0], fm = flags[4];
    const long xbase = (long)b_ * NTOK * 128;

    // zero VT pad cols 392..423: P=0 there, but 0*garbage-NaN would poison PV
    for (int i = tid; i < 32 * 32; i += 512){
        int d = i >> 5;
        VT[d * 424 + 392 + (i & 31)] = 0;
    }

    // ---------- phase 1: QKV projection via MFMA ----------
    // per 64-token chunk: 4 mtiles x 6 ntiles (n: 0-31=Q, 32-63=K, 64-95=V)
    const int mt  = wv >> 1;            // 0..3
    const int ntb = (wv & 1) * 3;       // ntiles ntb..ntb+2
    // hoist W fragments (same across chunks): 3 ntiles x 4 ksteps x hi/lo
    bf16x8 WH[3][4], WL[3][4];
    #pragma unroll
    for (int j = 0; j < 3; ++j){
        int n = (ntb + j) * 16 + c;
        int wrow = (n < 32) ? (h * 32 + n)
                 : (n < 64) ? (128 + h * 32 + (n - 32))
                 :            (256 + h * 32 + (n - 64));
        #pragma unroll
        for (int ks = 0; ks < 4; ++ks)
            ld8s(qwP, isb, (long)wrow * 128 + ks * 32 + 8 * g, &WH[j][ks], &WL[j][ks]);
    }

    for (int ch = 0; ch < 7; ++ch){
        const int tok0 = ch * 64;
        __syncthreads();                 // previous chunk's xs reads done
        #pragma unroll
        for (int jj = 0; jj < 4; ++jj){
            int idx = jj * 2048 + tid * 4;
            int r = idx >> 7, cc = idx & 127;
            int row = tok0 + r;
            u32 h01, h23, l01, l23;
            if (row < NTOK){
                long gi = xbase + (long)row * 128 + cc;
                if (isb){
                    uint2 a = *(const uint2*)((const u16*)xP + gi);
                    h01 = a.x; h23 = a.y; l01 = 0; l23 = 0;
                } else {
                    float4 f = *(const float4*)((const float*)xP + gi);
                    u16 h0=f2bf(f.x), h1=f2bf(f.y), h2=f2bf(f.z), h3=f2bf(f.w);
                    h01 = h0 | ((u32)h1 << 16); h23 = h2 | ((u32)h3 << 16);
                    l01 = (u32)f2bf(f.x - bf2f(h0)) | ((u32)f2bf(f.y - bf2f(h1)) << 16);
                    l23 = (u32)f2bf(f.z - bf2f(h2)) | ((u32)f2bf(f.w - bf2f(h3)) << 16);
                }
            } else { h01 = h23 = l01 = l23 = 0; }
            *(uint2*)&xs_hi[r * 136 + cc] = make_uint2(h01, h23);
            *(uint2*)&xs_lo[r * 136 + cc] = make_uint2(l01, l23);
        }
        __syncthreads();
        #pragma unroll
        for (int j = 0; j < 3; ++j){
            f32x4 acc = {0.f, 0.f, 0.f, 0.f};
            #pragma unroll
            for (int ks = 0; ks < 4; ++ks){
                bf16x8 ah = *(const bf16x8*)&xs_hi[(mt * 16 + c) * 136 + ks * 32 + 8 * g];
                bf16x8 al = *(const bf16x8*)&xs_lo[(mt * 16 + c) * 136 + ks * 32 + 8 * g];
                acc = MFMA16(ah, WH[j][ks], acc);
                acc = MFMA16(al, WH[j][ks], acc);
                acc = MFMA16(ah, WL[j][ks], acc);
            }
            int n = (ntb + j) * 16 + c;
            #pragma unroll
            for (int i = 0; i < 4; ++i){
                int tok = tok0 + mt * 16 + 4 * g + i;   // D row = 4g+i
                if (tok < NTOK){
                    if (n < 32)      Qh[tok * 40 + n]         = f2bf(acc[i] * QSCALE);
                    else if (n < 64) Kh[tok * 40 + (n - 32)]  = f2bf(acc[i]);
                    else             VT[(n - 64) * 424 + tok] = f2bf(acc[i]);
                }
            }
        }
    }
    __syncthreads();                     // Q/K/V complete & visible

    // ---------- phase 2: attention, wave-parallel over 16-row q-tiles ----------
    u16* pb = uni + wv * 640;            // per-wave 16x32 u16 P tile, stride 40
    for (int qt = wv; qt < 25; qt += 8){
        const int q0 = qt * 16;
        bf16x8 qa = *(const bf16x8*)&Qh[(q0 + c) * 40 + 8 * g];
        f32x4 o0 = {0.f,0.f,0.f,0.f}, o1 = {0.f,0.f,0.f,0.f};
        float rs0 = 0.f, rs1 = 0.f, rs2 = 0.f, rs3 = 0.f;
        int qr[4];
        #pragma unroll
        for (int i = 0; i < 4; ++i){
            int q = q0 + 4 * g + i;
            qr[i] = (q < NTOK) ? q : (NTOK - 1);
        }
        const float* bptr = biasfull + (long)h * NN2;
        // prefetch bias for kt = 0 (keys c, c < NTOK always)
        float bn0 = bptr[(long)qr[0] * NTOK + c];
        float bn1 = bptr[(long)qr[1] * NTOK + c];
        float bn2 = bptr[(long)qr[2] * NTOK + c];
        float bn3 = bptr[(long)qr[3] * NTOK + c];
        for (int kt = 0; kt < 26; ++kt){
            bf16x8 kb = *(const bf16x8*)&Kh[(kt * 16 + c) * 40 + 8 * g];
            f32x4 z = {0.f,0.f,0.f,0.f};
            f32x4 s = MFMA16(qa, kb, z);
            float b0 = bn0, b1 = bn1, b2 = bn2, b3 = bn3;
            if (kt < 25){
                int keyn = (kt + 1) * 16 + c; if (keyn >= NTOK) keyn = NTOK - 1;
                bn0 = bptr[(long)qr[0] * NTOK + keyn];
                bn1 = bptr[(long)qr[1] * NTOK + keyn];
                bn2 = bptr[(long)qr[2] * NTOK + keyn];
                bn3 = bptr[(long)qr[3] * NTOK + keyn];
            }
            int key = kt * 16 + c;
            if (fm){
                long mb = (long)wdx * NN2;
                int kc = (key < NTOK) ? key : (NTOK - 1);
                b0 += ldf(maskP, isb, mb + (long)qr[0] * NTOK + kc);
                b1 += ldf(maskP, isb, mb + (long)qr[1] * NTOK + kc);
                b2 += ldf(maskP, isb, mb + (long)qr[2] * NTOK + kc);
                b3 += ldf(maskP, isb, mb + (long)qr[3] * NTOK + kc);
            }
            bool kvld = key < NTOK;
            float p0 = kvld ? exp2f((s[0] + b0) * LOG2E) : 0.f;
            float p1 = kvld ? exp2f((s[1] + b1) * LOG2E) : 0.f;
            float p2 = kvld ? exp2f((s[2] + b2) * LOG2E) : 0.f;
            float p3 = kvld ? exp2f((s[3] + b3) * LOG2E) : 0.f;
            rs0 += p0; rs1 += p1; rs2 += p2; rs3 += p3;
            // write D-layout P half-tile (row=4g+i, col-in-32 = (kt&1)*16 + c)
            int co = (kt & 1) * 16 + c;
            pb[(4 * g + 0) * 40 + co] = f2bf(p0);
            pb[(4 * g + 1) * 40 + co] = f2bf(p1);
            pb[(4 * g + 2) * 40 + co] = f2bf(p2);
            pb[(4 * g + 3) * 40 + co] = f2bf(p3);
            if (kt & 1){
                // full 16x32 P tile ready: one PV MFMA pair over k = 0..31 keys
                bf16x8 pa = *(const bf16x8*)&pb[c * 40 + 8 * g];
                int kk = (kt >> 1) * 32 + 8 * g;
                bf16x8 v0 = *(const bf16x8*)&VT[c * 424 + kk];
                bf16x8 v1 = *(const bf16x8*)&VT[(c + 16) * 424 + kk];
                o0 = MFMA16(pa, v0, o0);
                o1 = MFMA16(pa, v1, o1);
            }
        }
        // row-sum reduce across the 16 lanes of each group (xor masks < 16 stay in group)
        #pragma unroll
        for (int m = 1; m < 16; m <<= 1){
            rs0 += __shfl_xor(rs0, m, 64);
            rs1 += __shfl_xor(rs1, m, 64);
            rs2 += __shfl_xor(rs2, m, 64);
            rs3 += __shfl_xor(rs3, m, 64);
        }
        float inv[4] = {1.f / rs0, 1.f / rs1, 1.f / rs2, 1.f / rs3};
        #pragma unroll
        for (int i = 0; i < 4; ++i){
            int tok = q0 + 4 * g + i;
            if (tok < NTOK){
                stf(outP, isb, xbase + (long)tok * 128 + h * 32 + c,      o0[i] * inv[i]);
                stf(outP, isb, xbase + (long)tok * 128 + h * 32 + 16 + c, o1[i] * inv[i]);
            }
        }
    }
}

// ---------- kernel E: out = O @ proj_w^T + proj_b (MFMA, in-place on d_out) ----------
__global__ __launch_bounds__(512) void proj_mfma_kernel(
        const void* wP, const void* bP, const int* __restrict__ flags,
        void* outP){
    __shared__ __align__(16) u16 xs_hi[64 * 136];
    __shared__ __align__(16) u16 xs_lo[64 * 136];   // 69632 B -> 2 blocks/CU
    const int tid  = threadIdx.x;
    const int lane = tid & 63;
    const int wv   = tid >> 6;
    const int c    = lane & 15;
    const int g    = lane >> 4;
    const int isb  = flags[0];
    const long m0  = (long)blockIdx.x * 64;

    #pragma unroll
    for (int jj = 0; jj < 4; ++jj){
        int idx = jj * 2048 + tid * 4;
        int r = idx >> 7, cc = idx & 127;
        long gi = (m0 + r) * 128 + cc;
        u32 h01, h23, l01, l23;
        if (isb){
            uint2 a = *(const uint2*)((const u16*)outP + gi);
            h01 = a.x; h23 = a.y; l01 = 0; l23 = 0;
        } else {
            float4 f = *(const float4*)((const float*)outP + gi);
            u16 h0=f2bf(f.x), h1=f2bf(f.y), h2=f2bf(f.z), h3=f2bf(f.w);
            h01 = h0 | ((u32)h1 << 16); h23 = h2 | ((u32)h3 << 16);
            l01 = (u32)f2bf(f.x - bf2f(h0)) | ((u32)f2bf(f.y - bf2f(h1)) << 16);
            l23 = (u32)f2bf(f.z - bf2f(h2)) | ((u32)f2bf(f.w - bf2f(h3)) << 16);
        }
        *(uint2*)&xs_hi[r * 136 + cc] = make_uint2(h01, h23);
        *(uint2*)&xs_lo[r * 136 + cc] = make_uint2(l01, l23);
    }
    __syncthreads();
    const int mt  = wv >> 1;             // 0..3
    const int ntb = (wv & 1) * 4;        // 4 ntiles each
    bf16x8 ah[4], al[4];
    #pragma unroll
    for (int ks = 0; ks < 4; ++ks){
        ah[ks] = *(const bf16x8*)&xs_hi[(mt * 16 + c) * 136 + ks * 32 + 8 * g];
        al[ks] = *(const bf16x8*)&xs_lo[(mt * 16 + c) * 136 + ks * 32 + 8 * g];
    }
    #pragma unroll
    for (int j = 0; j < 4; ++j){
        int nt = ntb + j;
        bf16x8 wh[4], wl[4];
        #pragma unroll
        for (int ks = 0; ks < 4; ++ks)
            ld8s(wP, isb, (long)(nt * 16 + c) * 128 + ks * 32 + 8 * g, &wh[ks], &wl[ks]);
        f32x4 acc = {0.f,0.f,0.f,0.f};
        #pragma unroll
        for (int ks = 0; ks < 4; ++ks){
            acc = MFMA16(ah[ks], wh[ks], acc);
            acc = MFMA16(al[ks], wh[ks], acc);
            acc = MFMA16(ah[ks], wl[ks], acc);
        }
        float bias = ldf(bP, isb, nt * 16 + c);
        #pragma unroll
        for (int i = 0; i < 4; ++i){
            long row = m0 + mt * 16 + 4 * g + i;
            stf(outP, isb, row * 128 + nt * 16 + c, acc[i] + bias);
        }
    }
}

// ---------- launch ----------
extern "C" void kernel_launch(void* const* d_in, const int* in_sizes, int n_in,
                              void* d_out, int out_size, void* d_ws, size_t ws_size,
                              hipStream_t stream){
    const void* x      = d_in[0];
    const void* mask   = d_in[1];
    const void* qkv_w  = d_in[2];
    const void* proj_w = d_in[3];
    const void* proj_b = d_in[4];
    const void* btab   = d_in[5];
    const int*  relidx = (const int*)d_in[6];

    int*   flags    = (int*)d_ws;
    float* biasfull = (float*)((char*)d_ws + 256);   // 4*392*392 fp32 = 2.46 MB

    prep_kernel<<<dim3(1), dim3(256), 0, stream>>>((const u16*)x, flags);
    int nhalf = in_sizes[1] / 2;
    mask_scan_kernel<<<dim3(2048), dim3(256), 0, stream>>>(
        (const u32*)mask, nhalf, flags, flags);
    bias_expand_kernel<<<dim3((NN2 + 255) / 256), dim3(256), 0, stream>>>(
        relidx, btab, flags, biasfull);
    attn_mfma_kernel<<<dim3(4, 512), dim3(512), 0, stream>>>(
        x, qkv_w, mask, biasfull, flags, d_out);
    proj_mfma_kernel<<<dim3(3136), dim3(512), 0, stream>>>(
        proj_w, proj_b, flags, d_out);
}

// Round 3
// 719.803 us; speedup vs baseline: 6.3995x; 1.1435x over previous
//
#include <hip/hip_runtime.h>

typedef unsigned short u16;
typedef unsigned int   u32;

// B_=512, N=392, C=128, nH=4, hd=32, nW=128
#define NTOK   392
#define NN2    153664      // 392*392
#define LOG2E  1.44269504088896340736f
#define QSCL   (0.17677669529663687f * 1.44269504088896340736f)   // QSCALE * LOG2E
#define BTQ    416         // biasT padded q dim
#define BTH    (416L*416L) // biasT per-head plane elems

typedef __attribute__((ext_vector_type(8))) __bf16 bf16x8;
typedef __attribute__((ext_vector_type(4))) float  f32x4;
#define MFMA16(a,b,c) __builtin_amdgcn_mfma_f32_16x16x32_bf16((a),(b),(c),0,0,0)

__device__ __forceinline__ float bf2f(u16 u){
    union { u32 i; float f; } v; v.i = ((u32)u) << 16; return v.f;
}
__device__ __forceinline__ u16 f2bf(float x){
    union { float f; u32 i; } v; v.f = x;
    u32 r = (v.i + 0x7FFFu + ((v.i >> 16) & 1u)) >> 16;
    return (u16)r;
}
__device__ __forceinline__ u16 bfbits(float x){
    union { __bf16 b; u16 u; } v; v.b = (__bf16)x; return v.u;
}
// adaptive loads/stores: isb=1 -> packed bf16 storage, isb=0 -> fp32 storage
__device__ __forceinline__ float ldf(const void* p, int isb, long i){
    if (isb) return bf2f(((const u16*)p)[i]);
    else     return ((const float*)p)[i];
}
__device__ __forceinline__ void stf(void* p, int isb, long i, float v){
    if (isb) ((u16*)p)[i] = f2bf(v);
    else     ((float*)p)[i] = v;
}

// load 8 consecutive values from global, split into hi/lo bf16 fragments.
__device__ __forceinline__ void ld8s(const void* p, int isb, long i0,
                                     bf16x8* h, bf16x8* l){
    union { u16 u[8]; bf16x8 v; } H, L;
    if (isb){
        const uint2* q = (const uint2*)((const u16*)p + i0);
        uint2 a = q[0], b = q[1];
        H.u[0]=(u16)a.x; H.u[1]=(u16)(a.x>>16); H.u[2]=(u16)a.y; H.u[3]=(u16)(a.y>>16);
        H.u[4]=(u16)b.x; H.u[5]=(u16)(b.x>>16); H.u[6]=(u16)b.y; H.u[7]=(u16)(b.y>>16);
        #pragma unroll
        for (int j = 0; j < 8; ++j) L.u[j] = 0;
    } else {
        const float4* q = (const float4*)((const float*)p + i0);
        float4 a = q[0], b = q[1];
        float f[8] = {a.x,a.y,a.z,a.w,b.x,b.y,b.z,b.w};
        #pragma unroll
        for (int j = 0; j < 8; ++j){
            u16 hh = f2bf(f[j]);
            H.u[j] = hh;
            L.u[j] = f2bf(f[j] - bf2f(hh));
        }
    }
    *h = H.v; *l = L.v;
}

// ---------- kernel A: storage-dtype detection on x ----------
__device__ __forceinline__ int plaus(u16 w){
    int e = (w >> 7) & 0xFF;
    return (w == 0) || (e >= 96 && e <= 145);
}
__global__ __launch_bounds__(256) void prep_kernel(
        const u16* __restrict__ x, int* __restrict__ flags){
    __shared__ int cnt[2];
    int tid = threadIdx.x;
    if (tid < 2) cnt[tid] = 0;
    __syncthreads();
    int p = plaus(x[tid]) + plaus(x[tid + 256]);
    if (p) atomicAdd(&cnt[0], p);
    int ez = ((tid & 1) == 0 && x[tid] == 0) + (((tid + 256) & 1) == 0 && x[tid + 256] == 0);
    if (ez) atomicAdd(&cnt[1], ez);
    __syncthreads();
    if (tid == 0){
        flags[0] = (cnt[1] < 64 && cnt[0] >= 436) ? 1 : 0;
        flags[4] = 0;
    }
}

// ---------- kernel B: mask nonzero scan ----------
__global__ __launch_bounds__(256) void mask_scan_kernel(
        const u32* __restrict__ m, int nhalf, const int* __restrict__ flagsRO,
        int* __restrict__ flags){
    long nw = flagsRO[0] ? nhalf : 2L * nhalf;
    long i0 = (long)blockIdx.x * 256 + threadIdx.x;
    u32 acc = 0;
    for (long i = i0; i < nw; i += (long)gridDim.x * 256) acc |= m[i];
    if (acc) atomicOr(&flags[4], 1);
}

// ---------- kernel C: transposed bias biasT[h][key(416)][q(416)] = bias*LOG2E ----------
// pad: key>=392 -> -1e30 (exp2 -> 0), q>=392 -> 0 (harmless, stores gated)
__global__ __launch_bounds__(256) void bias_expand_kernel(
        const int* __restrict__ rel_index, const void* btabP,
        const int* __restrict__ flags, float* __restrict__ biasT){
    long idx = (long)blockIdx.x * 256 + threadIdx.x;
    if (idx >= BTH) return;
    int key = (int)(idx / BTQ);
    int q   = (int)(idx - (long)key * BTQ);
    int isb = flags[0];
    float v0, v1, v2, v3;
    if (key >= NTOK){ v0 = v1 = v2 = v3 = -1e30f; }
    else if (q >= NTOK){ v0 = v1 = v2 = v3 = 0.f; }
    else {
        int t = rel_index[(long)q * NTOK + key];
        v0 = ldf(btabP, isb, (long)t * 4 + 0) * LOG2E;
        v1 = ldf(btabP, isb, (long)t * 4 + 1) * LOG2E;
        v2 = ldf(btabP, isb, (long)t * 4 + 2) * LOG2E;
        v3 = ldf(btabP, isb, (long)t * 4 + 3) * LOG2E;
    }
    biasT[0 * BTH + idx] = v0;
    biasT[1 * BTH + idx] = v1;
    biasT[2 * BTH + idx] = v2;
    biasT[3 * BTH + idx] = v3;
}

// ---------- kernel D: fused MFMA window attention ----------
// block = (window b_, head h), 512 threads = 8 waves, 1 block/CU.
// Phase 1: Q,K,V = x @ W^T via split hi/lo bf16 MFMA. Q pre-scaled by QSCALE*LOG2E.
// Phase 2: 13 tasks of 32 q-rows; each wave runs TWO independent 16-row streams
//   (shared Kh/VT LDS reads), bias enters as MFMA C-operand (float4, ring-2 prefetch),
//   exp2f direct, P bounced via per-wave LDS tile to A-layout, PV per 32-key pair.
__global__ __launch_bounds__(512) void attn_mfma_kernel(
        const void* xP, const void* qwP, const void* maskP,
        const float* __restrict__ biasT, const int* __restrict__ flags,
        void* outP){
    __shared__ __align__(16) u16 Qh[416 * 40];        // 33280 B  Q bf16 [tok][d]
    __shared__ __align__(16) u16 Kh[416 * 40];        // 33280 B  K bf16 [key][d]
    __shared__ __align__(16) u16 VT[32 * 424];        // 27136 B  V bf16 [d][key]
    __shared__ __align__(16) u16 uni[2 * 64 * 136];   // 34816 B  xs_hi/lo; ph2: P bounces
    // total 128512 B -> 1 block/CU, 8 waves

    u16* xs_hi = uni;
    u16* xs_lo = uni + 64 * 136;

    const int tid  = threadIdx.x;
    const int lane = tid & 63;
    const int wv   = tid >> 6;          // 0..7
    const int c    = lane & 15;
    const int g    = lane >> 4;
    const int h    = blockIdx.y;
    const int b_   = blockIdx.x;
    const int wdx  = b_ & 127;
    const int isb  = flags[0], fm = flags[4];
    const long xbase = (long)b_ * NTOK * 128;

    // zero pad rows/cols (NaN-proof: pads participate in MFMA/exp unconditionally)
    for (int i = tid; i < 24 * 40; i += 512){ Qh[392 * 40 + i] = 0; Kh[392 * 40 + i] = 0; }
    for (int i = tid; i < 32 * 32; i += 512) VT[(i >> 5) * 424 + 392 + (i & 31)] = 0;

    // ---------- phase 1: QKV projection via MFMA ----------
    const int mt  = wv >> 1;            // 0..3
    const int ntb = (wv & 1) * 3;       // ntiles ntb..ntb+2
    bf16x8 WH[3][4], WL[3][4];
    #pragma unroll
    for (int j = 0; j < 3; ++j){
        int n = (ntb + j) * 16 + c;
        int wrow = (n < 32) ? (h * 32 + n)
                 : (n < 64) ? (128 + h * 32 + (n - 32))
                 :            (256 + h * 32 + (n - 64));
        #pragma unroll
        for (int ks = 0; ks < 4; ++ks)
            ld8s(qwP, isb, (long)wrow * 128 + ks * 32 + 8 * g, &WH[j][ks], &WL[j][ks]);
    }

    for (int ch = 0; ch < 7; ++ch){
        const int tok0 = ch * 64;
        __syncthreads();
        #pragma unroll
        for (int jj = 0; jj < 4; ++jj){
            int idx = jj * 2048 + tid * 4;
            int r = idx >> 7, cc = idx & 127;
            int row = tok0 + r;
            u32 h01, h23, l01, l23;
            if (row < NTOK){
                long gi = xbase + (long)row * 128 + cc;
                if (isb){
                    uint2 a = *(const uint2*)((const u16*)xP + gi);
                    h01 = a.x; h23 = a.y; l01 = 0; l23 = 0;
                } else {
                    float4 f = *(const float4*)((const float*)xP + gi);
                    u16 h0=f2bf(f.x), h1=f2bf(f.y), h2=f2bf(f.z), h3=f2bf(f.w);
                    h01 = h0 | ((u32)h1 << 16); h23 = h2 | ((u32)h3 << 16);
                    l01 = (u32)f2bf(f.x - bf2f(h0)) | ((u32)f2bf(f.y - bf2f(h1)) << 16);
                    l23 = (u32)f2bf(f.z - bf2f(h2)) | ((u32)f2bf(f.w - bf2f(h3)) << 16);
                }
            } else { h01 = h23 = l01 = l23 = 0; }
            *(uint2*)&xs_hi[r * 136 + cc] = make_uint2(h01, h23);
            *(uint2*)&xs_lo[r * 136 + cc] = make_uint2(l01, l23);
        }
        __syncthreads();
        #pragma unroll
        for (int j = 0; j < 3; ++j){
            f32x4 acc = {0.f, 0.f, 0.f, 0.f};
            #pragma unroll
            for (int ks = 0; ks < 4; ++ks){
                bf16x8 ah = *(const bf16x8*)&xs_hi[(mt * 16 + c) * 136 + ks * 32 + 8 * g];
                bf16x8 al = *(const bf16x8*)&xs_lo[(mt * 16 + c) * 136 + ks * 32 + 8 * g];
                acc = MFMA16(ah, WH[j][ks], acc);
                acc = MFMA16(al, WH[j][ks], acc);
                acc = MFMA16(ah, WL[j][ks], acc);
            }
            int n = (ntb + j) * 16 + c;
            #pragma unroll
            for (int i = 0; i < 4; ++i){
                int tok = tok0 + mt * 16 + 4 * g + i;
                if (tok < NTOK){
                    if (n < 32)      Qh[tok * 40 + n]         = f2bf(acc[i] * QSCL);
                    else if (n < 64) Kh[tok * 40 + (n - 32)]  = f2bf(acc[i]);
                    else             VT[(n - 64) * 424 + tok] = f2bf(acc[i]);
                }
            }
        }
    }
    __syncthreads();                     // Q/K/V + pads complete & visible

    // ---------- phase 2 ----------
    u16* pbA = uni + wv * 1280;          // per-wave 16x32 P tile (stride 40)
    u16* pbB = pbA + 640;
    const float* bT = biasT + (long)h * BTH;
    const long mb = (long)wdx * NN2;

    for (int task = wv; task < 13; task += 8){
        const int qa0 = task * 32;
        const int qb0 = qa0 + 16;
        bf16x8 qA = *(const bf16x8*)&Qh[(qa0 + c) * 40 + 8 * g];
        bf16x8 qB = *(const bf16x8*)&Qh[(qb0 + c) * 40 + 8 * g];
        f32x4 oA0={0.f,0.f,0.f,0.f}, oA1={0.f,0.f,0.f,0.f};
        f32x4 oB0={0.f,0.f,0.f,0.f}, oB1={0.f,0.f,0.f,0.f};
        float rsA0=0.f,rsA1=0.f,rsA2=0.f,rsA3=0.f;
        float rsB0=0.f,rsB1=0.f,rsB2=0.f,rsB3=0.f;
        // bias base for (key = kt*16+c, q = q0+4g..+3); advance 16*BTQ floats per kt
        const float* bp = bT + (long)c * BTQ + qa0 + 4 * g;
        f32x4 rA0 = *(const f32x4*)(bp);
        f32x4 rB0 = *(const f32x4*)(bp + 16);
        f32x4 rA1 = *(const f32x4*)(bp + 16 * BTQ);
        f32x4 rB1 = *(const f32x4*)(bp + 16 * BTQ + 16);
        const float* fp = bp + 32 * BTQ;          // refill ptr (kt+2 for kt=0)

        for (int k2 = 0; k2 < 13; ++k2){
            // ---- even kt = 2*k2: P cols 0..15 of the pair ----
            {
                const int kt = 2 * k2;
                bf16x8 kb = *(const bf16x8*)&Kh[(kt * 16 + c) * 40 + 8 * g];
                f32x4 cA = rA0, cB = rB0;
                if (k2 < 12){
                    rA0 = *(const f32x4*)(fp);
                    rB0 = *(const f32x4*)(fp + 16);
                }
                if (fm){
                    int key = kt * 16 + c; int kc = key < NTOK ? key : NTOK - 1;
                    #pragma unroll
                    for (int i = 0; i < 4; ++i){
                        int qa_ = qa0 + 4 * g + i; if (qa_ >= NTOK) qa_ = NTOK - 1;
                        int qb_ = qb0 + 4 * g + i; if (qb_ >= NTOK) qb_ = NTOK - 1;
                        cA[i] += ldf(maskP, isb, mb + (long)qa_ * NTOK + kc) * LOG2E;
                        cB[i] += ldf(maskP, isb, mb + (long)qb_ * NTOK + kc) * LOG2E;
                    }
                }
                f32x4 sA = MFMA16(qA, kb, cA);
                f32x4 sB = MFMA16(qB, kb, cB);
                float pA[4], pB[4];
                #pragma unroll
                for (int i = 0; i < 4; ++i){ pA[i] = exp2f(sA[i]); pB[i] = exp2f(sB[i]); }
                rsA0 += pA[0]; rsA1 += pA[1]; rsA2 += pA[2]; rsA3 += pA[3];
                rsB0 += pB[0]; rsB1 += pB[1]; rsB2 += pB[2]; rsB3 += pB[3];
                #pragma unroll
                for (int i = 0; i < 4; ++i){
                    pbA[(4 * g + i) * 40 + c] = bfbits(pA[i]);
                    pbB[(4 * g + i) * 40 + c] = bfbits(pB[i]);
                }
            }
            // ---- odd kt = 2*k2+1: P cols 16..31, then PV over the 32-key pair ----
            {
                const int kt = 2 * k2 + 1;
                bf16x8 kb = *(const bf16x8*)&Kh[(kt * 16 + c) * 40 + 8 * g];
                f32x4 cA = rA1, cB = rB1;
                if (k2 < 12){
                    rA1 = *(const f32x4*)(fp + 16 * BTQ);
                    rB1 = *(const f32x4*)(fp + 16 * BTQ + 16);
                    fp += 32 * BTQ;
                }
                if (fm){
                    int key = kt * 16 + c; int kc = key < NTOK ? key : NTOK - 1;
                    #pragma unroll
                    for (int i = 0; i < 4; ++i){
                        int qa_ = qa0 + 4 * g + i; if (qa_ >= NTOK) qa_ = NTOK - 1;
                        int qb_ = qb0 + 4 * g + i; if (qb_ >= NTOK) qb_ = NTOK - 1;
                        cA[i] += ldf(maskP, isb, mb + (long)qa_ * NTOK + kc) * LOG2E;
                        cB[i] += ldf(maskP, isb, mb + (long)qb_ * NTOK + kc) * LOG2E;
                    }
                }
                f32x4 sA = MFMA16(qA, kb, cA);
                f32x4 sB = MFMA16(qB, kb, cB);
                float pA[4], pB[4];
                #pragma unroll
                for (int i = 0; i < 4; ++i){ pA[i] = exp2f(sA[i]); pB[i] = exp2f(sB[i]); }
                rsA0 += pA[0]; rsA1 += pA[1]; rsA2 += pA[2]; rsA3 += pA[3];
                rsB0 += pB[0]; rsB1 += pB[1]; rsB2 += pB[2]; rsB3 += pB[3];
                #pragma unroll
                for (int i = 0; i < 4; ++i){
                    pbA[(4 * g + i) * 40 + 16 + c] = bfbits(pA[i]);
                    pbB[(4 * g + i) * 40 + 16 + c] = bfbits(pB[i]);
                }
                bf16x8 paA = *(const bf16x8*)&pbA[c * 40 + 8 * g];
                bf16x8 paB = *(const bf16x8*)&pbB[c * 40 + 8 * g];
                int kk = k2 * 32 + 8 * g;
                bf16x8 v0 = *(const bf16x8*)&VT[c * 424 + kk];
                bf16x8 v1 = *(const bf16x8*)&VT[(c + 16) * 424 + kk];
                oA0 = MFMA16(paA, v0, oA0);
                oA1 = MFMA16(paA, v1, oA1);
                oB0 = MFMA16(paB, v0, oB0);
                oB1 = MFMA16(paB, v1, oB1);
            }
        }
        // row-sum reduce within each 16-lane group
        float rsA[4] = {rsA0, rsA1, rsA2, rsA3};
        float rsB[4] = {rsB0, rsB1, rsB2, rsB3};
        #pragma unroll
        for (int m = 1; m < 16; m <<= 1){
            #pragma unroll
            for (int i = 0; i < 4; ++i){
                rsA[i] += __shfl_xor(rsA[i], m, 64);
                rsB[i] += __shfl_xor(rsB[i], m, 64);
            }
        }
        #pragma unroll
        for (int i = 0; i < 4; ++i){
            int ta = qa0 + 4 * g + i;
            if (ta < NTOK){
                float ia = 1.f / rsA[i];
                stf(outP, isb, xbase + (long)ta * 128 + h * 32 + c,      oA0[i] * ia);
                stf(outP, isb, xbase + (long)ta * 128 + h * 32 + 16 + c, oA1[i] * ia);
            }
            int tb = qb0 + 4 * g + i;
            if (tb < NTOK){
                float ib = 1.f / rsB[i];
                stf(outP, isb, xbase + (long)tb * 128 + h * 32 + c,      oB0[i] * ib);
                stf(outP, isb, xbase + (long)tb * 128 + h * 32 + 16 + c, oB1[i] * ib);
            }
        }
    }
}

// ---------- kernel E: out = O @ proj_w^T + proj_b (MFMA, in-place on d_out) ----------
__global__ __launch_bounds__(512) void proj_mfma_kernel(
        const void* wP, const void* bP, const int* __restrict__ flags,
        void* outP){
    __shared__ __align__(16) u16 xs_hi[64 * 136];
    __shared__ __align__(16) u16 xs_lo[64 * 136];   // 69632 B -> 2 blocks/CU
    const int tid  = threadIdx.x;
    const int lane = tid & 63;
    const int wv   = tid >> 6;
    const int c    = lane & 15;
    const int g    = lane >> 4;
    const int isb  = flags[0];
    const long m0  = (long)blockIdx.x * 64;

    #pragma unroll
    for (int jj = 0; jj < 4; ++jj){
        int idx = jj * 2048 + tid * 4;
        int r = idx >> 7, cc = idx & 127;
        long gi = (m0 + r) * 128 + cc;
        u32 h01, h23, l01, l23;
        if (isb){
            uint2 a = *(const uint2*)((const u16*)outP + gi);
            h01 = a.x; h23 = a.y; l01 = 0; l23 = 0;
        } else {
            float4 f = *(const float4*)((const float*)outP + gi);
            u16 h0=f2bf(f.x), h1=f2bf(f.y), h2=f2bf(f.z), h3=f2bf(f.w);
            h01 = h0 | ((u32)h1 << 16); h23 = h2 | ((u32)h3 << 16);
            l01 = (u32)f2bf(f.x - bf2f(h0)) | ((u32)f2bf(f.y - bf2f(h1)) << 16);
            l23 = (u32)f2bf(f.z - bf2f(h2)) | ((u32)f2bf(f.w - bf2f(h3)) << 16);
        }
        *(uint2*)&xs_hi[r * 136 + cc] = make_uint2(h01, h23);
        *(uint2*)&xs_lo[r * 136 + cc] = make_uint2(l01, l23);
    }
    __syncthreads();
    const int mt  = wv >> 1;
    const int ntb = (wv & 1) * 4;
    bf16x8 ah[4], al[4];
    #pragma unroll
    for (int ks = 0; ks < 4; ++ks){
        ah[ks] = *(const bf16x8*)&xs_hi[(mt * 16 + c) * 136 + ks * 32 + 8 * g];
        al[ks] = *(const bf16x8*)&xs_lo[(mt * 16 + c) * 136 + ks * 32 + 8 * g];
    }
    #pragma unroll
    for (int j = 0; j < 4; ++j){
        int nt = ntb + j;
        bf16x8 wh[4], wl[4];
        #pragma unroll
        for (int ks = 0; ks < 4; ++ks)
            ld8s(wP, isb, (long)(nt * 16 + c) * 128 + ks * 32 + 8 * g, &wh[ks], &wl[ks]);
        f32x4 acc = {0.f,0.f,0.f,0.f};
        #pragma unroll
        for (int ks = 0; ks < 4; ++ks){
            acc = MFMA16(ah[ks], wh[ks], acc);
            acc = MFMA16(al[ks], wh[ks], acc);
            acc = MFMA16(ah[ks], wl[ks], acc);
        }
        float bias = ldf(bP, isb, nt * 16 + c);
        #pragma unroll
        for (int i = 0; i < 4; ++i){
            long row = m0 + mt * 16 + 4 * g + i;
            stf(outP, isb, row * 128 + nt * 16 + c, acc[i] + bias);
        }
    }
}

// ---------- launch ----------
extern "C" void kernel_launch(void* const* d_in, const int* in_sizes, int n_in,
                              void* d_out, int out_size, void* d_ws, size_t ws_size,
                              hipStream_t stream){
    const void* x      = d_in[0];
    const void* mask   = d_in[1];
    const void* qkv_w  = d_in[2];
    const void* proj_w = d_in[3];
    const void* proj_b = d_in[4];
    const void* btab   = d_in[5];
    const int*  relidx = (const int*)d_in[6];

    int*   flags = (int*)d_ws;
    float* biasT = (float*)((char*)d_ws + 256);   // 4*416*416 fp32 = 2.77 MB

    prep_kernel<<<dim3(1), dim3(256), 0, stream>>>((const u16*)x, flags);
    int nhalf = in_sizes[1] / 2;
    mask_scan_kernel<<<dim3(2048), dim3(256), 0, stream>>>(
        (const u32*)mask, nhalf, flags, flags);
    bias_expand_kernel<<<dim3((int)((BTH + 255) / 256)), dim3(256), 0, stream>>>(
        relidx, btab, flags, biasT);
    attn_mfma_kernel<<<dim3(512, 4), dim3(512), 0, stream>>>(
        x, qkv_w, mask, biasT, flags, d_out);
    proj_mfma_kernel<<<dim3(3136), dim3(512), 0, stream>>>(
        proj_w, proj_b, flags, d_out);
}

// Round 4
// 700.314 us; speedup vs baseline: 6.5776x; 1.0278x over previous
//
#include <hip/hip_runtime.h>

typedef unsigned short u16;
typedef unsigned int   u32;

// B_=512, N=392, C=128, nH=4, hd=32, nW=128
#define NTOK   392
#define NN2    153664      // 392*392
#define LOG2E  1.44269504088896340736f
#define QSCL   (0.17677669529663687f * 1.44269504088896340736f)   // QSCALE * LOG2E
#define BTK    416         // biasF padded key dim (and q dim)
#define BTH    (416L*416L) // biasF per-head plane elems

typedef __attribute__((ext_vector_type(8))) __bf16 bf16x8;
typedef __attribute__((ext_vector_type(4))) float  f32x4;
#define MFMA16(a,b,c) __builtin_amdgcn_mfma_f32_16x16x32_bf16((a),(b),(c),0,0,0)

__device__ __forceinline__ float bf2f(u16 u){
    union { u32 i; float f; } v; v.i = ((u32)u) << 16; return v.f;
}
__device__ __forceinline__ u16 f2bf(float x){
    union { float f; u32 i; } v; v.f = x;
    u32 r = (v.i + 0x7FFFu + ((v.i >> 16) & 1u)) >> 16;
    return (u16)r;
}
__device__ __forceinline__ u16 bfbits(float x){
    union { __bf16 b; u16 u; } v; v.b = (__bf16)x; return v.u;
}
__device__ __forceinline__ u32 pk2(float a, float b){
    return (u32)bfbits(a) | ((u32)bfbits(b) << 16);
}
// adaptive loads/stores: isb=1 -> packed bf16 storage, isb=0 -> fp32 storage
__device__ __forceinline__ float ldf(const void* p, int isb, long i){
    if (isb) return bf2f(((const u16*)p)[i]);
    else     return ((const float*)p)[i];
}
__device__ __forceinline__ void stf(void* p, int isb, long i, float v){
    if (isb) ((u16*)p)[i] = f2bf(v);
    else     ((float*)p)[i] = v;
}

// load 8 consecutive values from global, split into hi/lo bf16 fragments.
__device__ __forceinline__ void ld8s(const void* p, int isb, long i0,
                                     bf16x8* h, bf16x8* l){
    union { u16 u[8]; bf16x8 v; } H, L;
    if (isb){
        const uint2* q = (const uint2*)((const u16*)p + i0);
        uint2 a = q[0], b = q[1];
        H.u[0]=(u16)a.x; H.u[1]=(u16)(a.x>>16); H.u[2]=(u16)a.y; H.u[3]=(u16)(a.y>>16);
        H.u[4]=(u16)b.x; H.u[5]=(u16)(b.x>>16); H.u[6]=(u16)b.y; H.u[7]=(u16)(b.y>>16);
        #pragma unroll
        for (int j = 0; j < 8; ++j) L.u[j] = 0;
    } else {
        const float4* q = (const float4*)((const float*)p + i0);
        float4 a = q[0], b = q[1];
        float f[8] = {a.x,a.y,a.z,a.w,b.x,b.y,b.z,b.w};
        #pragma unroll
        for (int j = 0; j < 8; ++j){
            u16 hh = f2bf(f[j]);
            H.u[j] = hh;
            L.u[j] = f2bf(f[j] - bf2f(hh));
        }
    }
    *h = H.v; *l = L.v;
}

// ---------- kernel A: storage-dtype detection on x ----------
__device__ __forceinline__ int plaus(u16 w){
    int e = (w >> 7) & 0xFF;
    return (w == 0) || (e >= 96 && e <= 145);
}
__global__ __launch_bounds__(256) void prep_kernel(
        const u16* __restrict__ x, int* __restrict__ flags){
    __shared__ int cnt[2];
    int tid = threadIdx.x;
    if (tid < 2) cnt[tid] = 0;
    __syncthreads();
    int p = plaus(x[tid]) + plaus(x[tid + 256]);
    if (p) atomicAdd(&cnt[0], p);
    int ez = ((tid & 1) == 0 && x[tid] == 0) + (((tid + 256) & 1) == 0 && x[tid + 256] == 0);
    if (ez) atomicAdd(&cnt[1], ez);
    __syncthreads();
    if (tid == 0){
        flags[0] = (cnt[1] < 64 && cnt[0] >= 436) ? 1 : 0;
        flags[4] = 0;
    }
}

// ---------- kernel B: mask nonzero scan ----------
__global__ __launch_bounds__(256) void mask_scan_kernel(
        const u32* __restrict__ m, int nhalf, const int* __restrict__ flagsRO,
        int* __restrict__ flags){
    long nw = flagsRO[0] ? nhalf : 2L * nhalf;
    long i0 = (long)blockIdx.x * 256 + threadIdx.x;
    u32 acc = 0;
    for (long i = i0; i < nw; i += (long)gridDim.x * 256) acc |= m[i];
    if (acc) atomicOr(&flags[4], 1);
}

// ---------- kernel C: bias biasF[h][q(416)][key(416)] = bias*LOG2E ----------
// pad: key>=392 -> -1e30 (exp2 -> 0), q>=392 -> 0 (harmless, stores gated)
__global__ __launch_bounds__(256) void bias_expand_kernel(
        const int* __restrict__ rel_index, const void* btabP,
        const int* __restrict__ flags, float* __restrict__ biasF){
    long idx = (long)blockIdx.x * 256 + threadIdx.x;
    if (idx >= BTH) return;
    int q   = (int)(idx / BTK);
    int key = (int)(idx - (long)q * BTK);
    int isb = flags[0];
    float v0, v1, v2, v3;
    if (key >= NTOK){ v0 = v1 = v2 = v3 = -1e30f; }
    else if (q >= NTOK){ v0 = v1 = v2 = v3 = 0.f; }
    else {
        int t = rel_index[(long)q * NTOK + key];
        v0 = ldf(btabP, isb, (long)t * 4 + 0) * LOG2E;
        v1 = ldf(btabP, isb, (long)t * 4 + 1) * LOG2E;
        v2 = ldf(btabP, isb, (long)t * 4 + 2) * LOG2E;
        v3 = ldf(btabP, isb, (long)t * 4 + 3) * LOG2E;
    }
    biasF[0 * BTH + idx] = v0;
    biasF[1 * BTH + idx] = v1;
    biasF[2 * BTH + idx] = v2;
    biasF[3 * BTH + idx] = v3;
}

// ---------- kernel D: fused MFMA window attention ----------
// block = (window b_, head h), 832 threads = 13 waves, 1 block/CU.
// Phase 1: Q,K,V = x @ W^T via MFMA; hi/lo split only when fp32 storage (isb=0).
//   24 (mt,nt) tile-jobs per 64-token chunk over 13 waves (2 rounds).
// Phase 2: 13 tasks of 32 q-rows, exactly ONE per wave (perfect balance).
//   Swapped QK^T: S = mfma(K, Q) so each lane holds 4 keys of one q-row ->
//   P written as ds_write_b64 (packed), bias [q][key] float4 as MFMA C-operand,
//   row-sum = scalar + shfl_xor(16,32), PV per 32-key pair from VT.
__global__ __launch_bounds__(832) void attn_mfma_kernel(
        const void* xP, const void* qwP, const void* maskP,
        const float* __restrict__ biasF, const int* __restrict__ flags,
        void* outP){
    __shared__ __align__(16) u16 Qh[416 * 40];        // 33280 B  Q bf16 [tok][d]
    __shared__ __align__(16) u16 Kh[416 * 40];        // 33280 B  K bf16 [key][d]
    __shared__ __align__(16) u16 VT[32 * 424];        // 27136 B  V bf16 [d][key]
    __shared__ __align__(16) u16 uni[2 * 64 * 136];   // 34816 B  xs_hi/lo; ph2: P bounces
    // total 128512 B -> 1 block/CU, 13 waves

    u16* xs_hi = uni;
    u16* xs_lo = uni + 64 * 136;

    const int tid  = threadIdx.x;
    const int lane = tid & 63;
    const int wv   = tid >> 6;          // 0..12
    const int c    = lane & 15;
    const int g    = lane >> 4;
    const int h    = blockIdx.y;
    const int b_   = blockIdx.x;
    const int wdx  = b_ & 127;
    const int isb  = flags[0], fm = flags[4];
    const long xbase = (long)b_ * NTOK * 128;

    // zero pad rows/cols (NaN-proof: pads participate in MFMA/exp unconditionally)
    for (int i = tid; i < 24 * 40; i += 832){ Qh[392 * 40 + i] = 0; Kh[392 * 40 + i] = 0; }
    for (int i = tid; i < 32 * 32; i += 832) VT[(i >> 5) * 424 + 392 + (i & 31)] = 0;

    // ---------- phase 1: QKV projection via MFMA ----------
    // jobs 0..23 = (nt = job>>2, mt = job&3); wave wv does jobs {wv, wv+13}
    const int nt0 = wv >> 2,        mt0 = wv & 3;
    const int nt1 = (wv + 13) >> 2, mt1 = (wv + 13) & 3;
    const int has1 = (wv < 11);
    bf16x8 W0h[4], W0l[4], W1h[4], W1l[4];
    {
        int n0 = nt0 * 16 + c;
        int wr0 = (n0 < 32) ? (h * 32 + n0)
                : (n0 < 64) ? (128 + h * 32 + (n0 - 32))
                :             (256 + h * 32 + (n0 - 64));
        int n1 = nt1 * 16 + c;
        int wr1 = (n1 < 32) ? (h * 32 + n1)
                : (n1 < 64) ? (128 + h * 32 + (n1 - 32))
                :             (256 + h * 32 + (n1 - 64));
        #pragma unroll
        for (int ks = 0; ks < 4; ++ks){
            ld8s(qwP, isb, (long)wr0 * 128 + ks * 32 + 8 * g, &W0h[ks], &W0l[ks]);
            if (has1)
                ld8s(qwP, isb, (long)wr1 * 128 + ks * 32 + 8 * g, &W1h[ks], &W1l[ks]);
        }
    }

    for (int ch = 0; ch < 7; ++ch){
        const int tok0 = ch * 64;
        __syncthreads();
        for (int idx = tid * 4; idx < 8192; idx += 3328){
            int r = idx >> 7, cc = idx & 127;
            int row = tok0 + r;
            if (isb){
                uint2 a = make_uint2(0u, 0u);
                if (row < NTOK)
                    a = *(const uint2*)((const u16*)xP + xbase + (long)row * 128 + cc);
                *(uint2*)&xs_hi[r * 136 + cc] = a;
            } else {
                u32 h01, h23, l01, l23;
                if (row < NTOK){
                    float4 f = *(const float4*)((const float*)xP + xbase + (long)row * 128 + cc);
                    u16 h0=f2bf(f.x), h1=f2bf(f.y), h2=f2bf(f.z), h3=f2bf(f.w);
                    h01 = h0 | ((u32)h1 << 16); h23 = h2 | ((u32)h3 << 16);
                    l01 = (u32)f2bf(f.x - bf2f(h0)) | ((u32)f2bf(f.y - bf2f(h1)) << 16);
                    l23 = (u32)f2bf(f.z - bf2f(h2)) | ((u32)f2bf(f.w - bf2f(h3)) << 16);
                } else { h01 = h23 = l01 = l23 = 0; }
                *(uint2*)&xs_hi[r * 136 + cc] = make_uint2(h01, h23);
                *(uint2*)&xs_lo[r * 136 + cc] = make_uint2(l01, l23);
            }
        }
        __syncthreads();
        // job 0
        {
            f32x4 acc = {0.f, 0.f, 0.f, 0.f};
            #pragma unroll
            for (int ks = 0; ks < 4; ++ks){
                bf16x8 ah = *(const bf16x8*)&xs_hi[(mt0 * 16 + c) * 136 + ks * 32 + 8 * g];
                acc = MFMA16(ah, W0h[ks], acc);
                if (!isb){
                    bf16x8 al = *(const bf16x8*)&xs_lo[(mt0 * 16 + c) * 136 + ks * 32 + 8 * g];
                    acc = MFMA16(al, W0h[ks], acc);
                    acc = MFMA16(ah, W0l[ks], acc);
                }
            }
            int n = nt0 * 16 + c;
            #pragma unroll
            for (int i = 0; i < 4; ++i){
                int tok = tok0 + mt0 * 16 + 4 * g + i;
                if (tok < NTOK){
                    if (n < 32)      Qh[tok * 40 + n]         = f2bf(acc[i] * QSCL);
                    else if (n < 64) Kh[tok * 40 + (n - 32)]  = f2bf(acc[i]);
                    else             VT[(n - 64) * 424 + tok] = f2bf(acc[i]);
                }
            }
        }
        // job 1
        if (has1){
            f32x4 acc = {0.f, 0.f, 0.f, 0.f};
            #pragma unroll
            for (int ks = 0; ks < 4; ++ks){
                bf16x8 ah = *(const bf16x8*)&xs_hi[(mt1 * 16 + c) * 136 + ks * 32 + 8 * g];
                acc = MFMA16(ah, W1h[ks], acc);
                if (!isb){
                    bf16x8 al = *(const bf16x8*)&xs_lo[(mt1 * 16 + c) * 136 + ks * 32 + 8 * g];
                    acc = MFMA16(al, W1h[ks], acc);
                    acc = MFMA16(ah, W1l[ks], acc);
                }
            }
            int n = nt1 * 16 + c;
            #pragma unroll
            for (int i = 0; i < 4; ++i){
                int tok = tok0 + mt1 * 16 + 4 * g + i;
                if (tok < NTOK){
                    if (n < 32)      Qh[tok * 40 + n]         = f2bf(acc[i] * QSCL);
                    else if (n < 64) Kh[tok * 40 + (n - 32)]  = f2bf(acc[i]);
                    else             VT[(n - 64) * 424 + tok] = f2bf(acc[i]);
                }
            }
        }
    }
    __syncthreads();                     // Q/K/V + pads complete & visible

    // ---------- phase 2: ONE 32-row task per wave ----------
    u16* pbA = uni + wv * 1280;          // per-wave 16x32 P tiles (stride 40)
    u16* pbB = pbA + 640;
    const int qa0 = wv * 32, qb0 = qa0 + 16;
    const float* bpA = biasF + (long)h * BTH + (long)(qa0 + c) * BTK;
    const float* bpB = biasF + (long)h * BTH + (long)(qb0 + c) * BTK;
    const long mbase = (long)wdx * NN2;

    bf16x8 qA = *(const bf16x8*)&Qh[(qa0 + c) * 40 + 8 * g];
    bf16x8 qB = *(const bf16x8*)&Qh[(qb0 + c) * 40 + 8 * g];
    f32x4 oA0={0.f,0.f,0.f,0.f}, oA1={0.f,0.f,0.f,0.f};
    f32x4 oB0={0.f,0.f,0.f,0.f}, oB1={0.f,0.f,0.f,0.f};
    float rsA = 0.f, rsB = 0.f;
    f32x4 rAe = *(const f32x4*)(bpA + 4 * g);
    f32x4 rAo = *(const f32x4*)(bpA + 16 + 4 * g);
    f32x4 rBe = *(const f32x4*)(bpB + 4 * g);
    f32x4 rBo = *(const f32x4*)(bpB + 16 + 4 * g);

    for (int k2 = 0; k2 < 13; ++k2){
        const int kk = k2 * 32;
        f32x4 cAe = rAe, cAo = rAo, cBe = rBe, cBo = rBo;
        if (k2 < 12){
            rAe = *(const f32x4*)(bpA + kk + 32 + 4 * g);
            rAo = *(const f32x4*)(bpA + kk + 48 + 4 * g);
            rBe = *(const f32x4*)(bpB + kk + 32 + 4 * g);
            rBo = *(const f32x4*)(bpB + kk + 48 + 4 * g);
        }
        if (fm){
            int qa_ = qa0 + c; if (qa_ >= NTOK) qa_ = NTOK - 1;
            int qb_ = qb0 + c; if (qb_ >= NTOK) qb_ = NTOK - 1;
            #pragma unroll
            for (int i = 0; i < 4; ++i){
                int ke = kk + 4 * g + i;      int kce = ke < NTOK ? ke : NTOK - 1;
                int ko = kk + 16 + 4 * g + i; int kco = ko < NTOK ? ko : NTOK - 1;
                cAe[i] += ldf(maskP, isb, mbase + (long)qa_ * NTOK + kce) * LOG2E;
                cAo[i] += ldf(maskP, isb, mbase + (long)qa_ * NTOK + kco) * LOG2E;
                cBe[i] += ldf(maskP, isb, mbase + (long)qb_ * NTOK + kce) * LOG2E;
                cBo[i] += ldf(maskP, isb, mbase + (long)qb_ * NTOK + kco) * LOG2E;
            }
        }
        bf16x8 kbE = *(const bf16x8*)&Kh[(kk + c) * 40 + 8 * g];
        bf16x8 kbO = *(const bf16x8*)&Kh[(kk + 16 + c) * 40 + 8 * g];
        f32x4 sAe = MFMA16(kbE, qA, cAe);
        f32x4 sAo = MFMA16(kbO, qA, cAo);
        f32x4 sBe = MFMA16(kbE, qB, cBe);
        f32x4 sBo = MFMA16(kbO, qB, cBo);
        float pAe[4], pAo[4], pBe[4], pBo[4];
        #pragma unroll
        for (int i = 0; i < 4; ++i){
            pAe[i] = exp2f(sAe[i]); pAo[i] = exp2f(sAo[i]);
            pBe[i] = exp2f(sBe[i]); pBo[i] = exp2f(sBo[i]);
        }
        rsA += ((pAe[0]+pAe[1]) + (pAe[2]+pAe[3])) + ((pAo[0]+pAo[1]) + (pAo[2]+pAo[3]));
        rsB += ((pBe[0]+pBe[1]) + (pBe[2]+pBe[3])) + ((pBo[0]+pBo[1]) + (pBo[2]+pBo[3]));
        *(uint2*)&pbA[c * 40 + 4 * g]      = make_uint2(pk2(pAe[0],pAe[1]), pk2(pAe[2],pAe[3]));
        *(uint2*)&pbA[c * 40 + 16 + 4 * g] = make_uint2(pk2(pAo[0],pAo[1]), pk2(pAo[2],pAo[3]));
        *(uint2*)&pbB[c * 40 + 4 * g]      = make_uint2(pk2(pBe[0],pBe[1]), pk2(pBe[2],pBe[3]));
        *(uint2*)&pbB[c * 40 + 16 + 4 * g] = make_uint2(pk2(pBo[0],pBo[1]), pk2(pBo[2],pBo[3]));
        bf16x8 paA = *(const bf16x8*)&pbA[c * 40 + 8 * g];
        bf16x8 paB = *(const bf16x8*)&pbB[c * 40 + 8 * g];
        bf16x8 v0 = *(const bf16x8*)&VT[c * 424 + kk + 8 * g];
        bf16x8 v1 = *(const bf16x8*)&VT[(c + 16) * 424 + kk + 8 * g];
        oA0 = MFMA16(paA, v0, oA0);
        oA1 = MFMA16(paA, v1, oA1);
        oB0 = MFMA16(paB, v0, oB0);
        oB1 = MFMA16(paB, v1, oB1);
    }
    // full row sums: reduce across the 4 g-groups (lanes c, c+16, c+32, c+48)
    rsA += __shfl_xor(rsA, 16, 64); rsA += __shfl_xor(rsA, 32, 64);
    rsB += __shfl_xor(rsB, 16, 64); rsB += __shfl_xor(rsB, 32, 64);
    #pragma unroll
    for (int i = 0; i < 4; ++i){
        float SA = __shfl(rsA, 4 * g + i, 64);    // lane 4g+i has c == 4g+i
        float SB = __shfl(rsB, 4 * g + i, 64);
        int ta = qa0 + 4 * g + i;
        if (ta < NTOK){
            float ia = 1.f / SA;
            stf(outP, isb, xbase + (long)ta * 128 + h * 32 + c,      oA0[i] * ia);
            stf(outP, isb, xbase + (long)ta * 128 + h * 32 + 16 + c, oA1[i] * ia);
        }
        int tb = qb0 + 4 * g + i;
        if (tb < NTOK){
            float ib = 1.f / SB;
            stf(outP, isb, xbase + (long)tb * 128 + h * 32 + c,      oB0[i] * ib);
            stf(outP, isb, xbase + (long)tb * 128 + h * 32 + 16 + c, oB1[i] * ib);
        }
    }
}

// ---------- kernel E: out = O @ proj_w^T + proj_b (MFMA, in-place on d_out) ----------
__global__ __launch_bounds__(512) void proj_mfma_kernel(
        const void* wP, const void* bP, const int* __restrict__ flags,
        void* outP){
    __shared__ __align__(16) u16 xs_hi[64 * 136];
    __shared__ __align__(16) u16 xs_lo[64 * 136];   // 69632 B -> 2 blocks/CU
    const int tid  = threadIdx.x;
    const int lane = tid & 63;
    const int wv   = tid >> 6;
    const int c    = lane & 15;
    const int g    = lane >> 4;
    const int isb  = flags[0];
    const long m0  = (long)blockIdx.x * 64;

    #pragma unroll
    for (int jj = 0; jj < 4; ++jj){
        int idx = jj * 2048 + tid * 4;
        int r = idx >> 7, cc = idx & 127;
        long gi = (m0 + r) * 128 + cc;
        if (isb){
            uint2 a = *(const uint2*)((const u16*)outP + gi);
            *(uint2*)&xs_hi[r * 136 + cc] = a;
        } else {
            float4 f = *(const float4*)((const float*)outP + gi);
            u16 h0=f2bf(f.x), h1=f2bf(f.y), h2=f2bf(f.z), h3=f2bf(f.w);
            u32 h01 = h0 | ((u32)h1 << 16), h23 = h2 | ((u32)h3 << 16);
            u32 l01 = (u32)f2bf(f.x - bf2f(h0)) | ((u32)f2bf(f.y - bf2f(h1)) << 16);
            u32 l23 = (u32)f2bf(f.z - bf2f(h2)) | ((u32)f2bf(f.w - bf2f(h3)) << 16);
            *(uint2*)&xs_hi[r * 136 + cc] = make_uint2(h01, h23);
            *(uint2*)&xs_lo[r * 136 + cc] = make_uint2(l01, l23);
        }
    }
    __syncthreads();
    const int mt  = wv >> 1;
    const int ntb = (wv & 1) * 4;
    bf16x8 ah[4], al[4];
    #pragma unroll
    for (int ks = 0; ks < 4; ++ks){
        ah[ks] = *(const bf16x8*)&xs_hi[(mt * 16 + c) * 136 + ks * 32 + 8 * g];
        if (!isb)
            al[ks] = *(const bf16x8*)&xs_lo[(mt * 16 + c) * 136 + ks * 32 + 8 * g];
    }
    #pragma unroll
    for (int j = 0; j < 4; ++j){
        int nt = ntb + j;
        bf16x8 wh[4], wl[4];
        #pragma unroll
        for (int ks = 0; ks < 4; ++ks)
            ld8s(wP, isb, (long)(nt * 16 + c) * 128 + ks * 32 + 8 * g, &wh[ks], &wl[ks]);
        f32x4 acc = {0.f,0.f,0.f,0.f};
        #pragma unroll
        for (int ks = 0; ks < 4; ++ks){
            acc = MFMA16(ah[ks], wh[ks], acc);
            if (!isb){
                acc = MFMA16(al[ks], wh[ks], acc);
                acc = MFMA16(ah[ks], wl[ks], acc);
            }
        }
        float bias = ldf(bP, isb, nt * 16 + c);
        #pragma unroll
        for (int i = 0; i < 4; ++i){
            long row = m0 + mt * 16 + 4 * g + i;
            stf(outP, isb, row * 128 + nt * 16 + c, acc[i] + bias);
        }
    }
}

// ---------- launch ----------
extern "C" void kernel_launch(void* const* d_in, const int* in_sizes, int n_in,
                              void* d_out, int out_size, void* d_ws, size_t ws_size,
                              hipStream_t stream){
    const void* x      = d_in[0];
    const void* mask   = d_in[1];
    const void* qkv_w  = d_in[2];
    const void* proj_w = d_in[3];
    const void* proj_b = d_in[4];
    const void* btab   = d_in[5];
    const int*  relidx = (const int*)d_in[6];

    int*   flags = (int*)d_ws;
    float* biasF = (float*)((char*)d_ws + 256);   // 4*416*416 fp32 = 2.77 MB

    prep_kernel<<<dim3(1), dim3(256), 0, stream>>>((const u16*)x, flags);
    int nhalf = in_sizes[1] / 2;
    mask_scan_kernel<<<dim3(2048), dim3(256), 0, stream>>>(
        (const u32*)mask, nhalf, flags, flags);
    bias_expand_kernel<<<dim3((int)((BTH + 255) / 256)), dim3(256), 0, stream>>>(
        relidx, btab, flags, biasF);
    attn_mfma_kernel<<<dim3(512, 4), dim3(832), 0, stream>>>(
        x, qkv_w, mask, biasF, flags, d_out);
    proj_mfma_kernel<<<dim3(3136), dim3(512), 0, stream>>>(
        proj_w, proj_b, flags, d_out);
}